// Round 3
// baseline (116.395 us; speedup 1.0000x reference)
//
#include <hip/hip_runtime.h>
#include <hip/hip_bf16.h>

typedef __attribute__((ext_vector_type(8))) short short8;
typedef __attribute__((ext_vector_type(4))) float f32x4;
typedef unsigned short u16;
typedef unsigned int u32;

// B=512, M=40, H=128, D=64, C=128.
// Factored algebra: out[c,d] = sum_m x0[m,d] * T_m[c,d],
//   T_m[c,d] = sum_h W[c,h,m] * xk[h,d]   (pure bf16 GEMM, K=H=128)
// Telescoped (Abel): T accumulates over m, out += (s_m - s_{m+1}) * T_cum.
#define NB 512
#define NM 40
#define NH 128
#define ND 64
#define NC 128
#define KTOT 5120

__device__ __forceinline__ u16 f2bf_rne(float f) {
    u32 u = __float_as_uint(f);
    u32 r = u + 0x7FFFu + ((u >> 16) & 1u);
    return (u16)(r >> 16);
}

// W fp32 [C][h*40+m] -> bf16 W3 [n=m*16+t*4+q][c][8j], h = t*32+q*8+j.
// grid 256 = c(128) x mhalf(2); float4 loads. (Proven in rounds 0-1.)
__global__ void w3_kernel(const float* __restrict__ W, u16* __restrict__ W3) {
    __shared__ u16 kbuf[NH * 20];          // [h][mo], m-half only
    const int c = blockIdx.x >> 1, mh = blockIdx.x & 1;
    const float* src = W + (size_t)c * KTOT + mh * 20;
    for (int i = threadIdx.x; i < NH * 5; i += 256) {   // i = h*5 + j4
        int h = i / 5, j4 = i % 5;
        float4 v = *(const float4*)(src + h * NM + j4 * 4);
        u16* kb = kbuf + h * 20 + j4 * 4;
        kb[0] = f2bf_rne(v.x); kb[1] = f2bf_rne(v.y);
        kb[2] = f2bf_rne(v.z); kb[3] = f2bf_rne(v.w);
    }
    __syncthreads();
    for (int i = threadIdx.x; i < 320; i += 256) {      // i = mo*16 + t*4 + q
        int mo = i >> 4, t = (i >> 2) & 3, q = i & 3;
        int n = (mh * 20 + mo) * 16 + t * 4 + q;
        union { short8 s8; u16 e[8]; } v;
#pragma unroll
        for (int j = 0; j < 8; ++j)
            v.e[j] = kbuf[(t * 32 + q * 8 + j) * 20 + mo];
        *(short8*)(W3 + ((size_t)n * 128 + c) * 8) = v.s8;
    }
}

// main: grid 512 (1 batch/block), 512 thr = 8 waves = rh(8).
// Wave tile: 16 c-rows x 64 d-cols, all 40 m. Acc = T[4]+o[4] = 32 regs
// (vs round-1's 128), total ~122 regs -> 4 waves/SIMD (round-1 bottleneck
// was occupancy: 2 waves/SIMD, MfmaUtil 35%).
// A-frags loaded straight from L2 per lane (proven round-1 mechanism;
// LDS staging saves no L2 traffic since waves read disjoint c-slices),
// depth-2 register ring, compiler-managed waits, NO in-loop barriers.
// One A-load (16B/lane) feeds 4 MFMAs. B register-cached (m-invariant).
__global__ void __launch_bounds__(512, 4) cin_main(
    const float* __restrict__ x0g, const float* __restrict__ xkg,
    const float* __restrict__ biasg, const u16* __restrict__ W3,
    float* __restrict__ out)
{
    // xkT bf16 [64][144] = 18432 | x0s f32 [40][68] = 10880 @18432
    // bias 512 @29312 ; total 29824 B (2 blocks/CU -> 60 KiB/CU)
    __shared__ __align__(16) char smem[29824];
    short* xkT    = (short*)smem;
    float* x0s    = (float*)(smem + 18432);
    float* bias_s = (float*)(smem + 29312);

    const int tid = threadIdx.x;
    const int w = tid >> 6, L = tid & 63;
    const int q = L >> 4, l16 = L & 15;
    const int rh = w;                       // c base = rh*16
    const size_t b = blockIdx.x;

    // A-frag source for body u (= m*4+t): shorts
    //   W3[u*4096 + q*1024 + (rh*16+l16)*8 .. +8)
    // = W[c=rh*16+l16][h=t*32+q*8+j][m], MFMA A row=l16, k=q*8+j.
    const u16* Ap = W3 + q * 1024 + (size_t)(rh * 16 + l16) * 8;

    short8 aP[2];                           // depth-2 register ring
    aP[0] = *(const short8*)(Ap + 0 * 4096);
    aP[1] = *(const short8*)(Ap + 1 * 4096);

    // ---- prologue: xk -> bf16 xkT (transposed, stride 144), x0 -> LDS
    for (int i = tid; i < 2048; i += 512) {           // (h, d4)
        int h = i >> 4, d4 = (i & 15) << 2;
        float4 v = *(const float4*)(xkg + b * (NH * ND) + h * ND + d4);
        xkT[(d4 + 0) * 144 + h] = (short)f2bf_rne(v.x);
        xkT[(d4 + 1) * 144 + h] = (short)f2bf_rne(v.y);
        xkT[(d4 + 2) * 144 + h] = (short)f2bf_rne(v.z);
        xkT[(d4 + 3) * 144 + h] = (short)f2bf_rne(v.w);
    }
    for (int i = tid; i < 640; i += 512) {            // (m, d4)
        int m = i >> 4, d4 = (i & 15) << 2;
        *(f32x4*)(x0s + m * 68 + d4) =
            *(const f32x4*)(x0g + b * (NM * ND) + m * ND + d4);
    }
    if (tid < NC) bias_s[tid] = biasg[tid];
    __syncthreads();

    // B frag register cache: bR[t][n] = xk[h=t*32+q*8+j][d=n*16+l16]
    const short* Bp = xkT + (size_t)l16 * 144 + q * 8;
    short8 bR[4][4];
#pragma unroll
    for (int t = 0; t < 4; ++t)
#pragma unroll
        for (int n = 0; n < 4; ++n)
            bR[t][n] = *(const short8*)(Bp + n * (16 * 144) + t * 32);

    float s[4], sn[4];
#pragma unroll
    for (int n = 0; n < 4; ++n)
        s[n] = x0s[n * 16 + l16];            // m = 0

    f32x4 T[4] = {{0.f,0.f,0.f,0.f},{0.f,0.f,0.f,0.f},{0.f,0.f,0.f,0.f},{0.f,0.f,0.f,0.f}};
    f32x4 o[4] = {{0.f,0.f,0.f,0.f},{0.f,0.f,0.f,0.f},{0.f,0.f,0.f,0.f},{0.f,0.f,0.f,0.f}};

#pragma unroll 4
    for (int u = 0; u < 160; ++u) {          // u = m*4 + t
        const int t = u & 3;
        const short8 a = aP[u & 1];
        // prefetch body u+2 into the slot just consumed (clamped tail:
        // redundant reload of the last tile, harmless)
        const int up = (u + 2 < 160) ? (u + 2) : 159;
        aP[u & 1] = *(const short8*)(Ap + (size_t)up * 4096);
        if (t == 0) {
            const int m = u >> 2;
#pragma unroll
            for (int n = 0; n < 4; ++n)
                sn[n] = (m < 39) ? x0s[(m + 1) * 68 + n * 16 + l16] : 0.f;
        }
        T[0] = __builtin_amdgcn_mfma_f32_16x16x32_bf16(a, bR[t][0], T[0], 0, 0, 0);
        T[1] = __builtin_amdgcn_mfma_f32_16x16x32_bf16(a, bR[t][1], T[1], 0, 0, 0);
        T[2] = __builtin_amdgcn_mfma_f32_16x16x32_bf16(a, bR[t][2], T[2], 0, 0, 0);
        T[3] = __builtin_amdgcn_mfma_f32_16x16x32_bf16(a, bR[t][3], T[3], 0, 0, 0);
        if (t == 3) {        // telescoped scale: out += (s_m - s_{m+1}) * T
#pragma unroll
            for (int n = 0; n < 4; ++n) {
                const float dd = s[n] - sn[n];
                o[n] += dd * T[n];
                s[n] = sn[n];
            }
        }
    }

    // ---- epilogue: direct store, wave owns c in [rh*16, rh*16+16)
    // C/D layout: col = lane&15 (d), row = (lane>>4)*4 + reg (c offset)
    float* op = out + b * (NC * ND);
#pragma unroll
    for (int n = 0; n < 4; ++n) {
        const int d = n * 16 + l16;
#pragma unroll
        for (int rr = 0; rr < 4; ++rr) {
            const int c = rh * 16 + q * 4 + rr;
            op[c * ND + d] = o[n][rr] + bias_s[c];
        }
    }
}

extern "C" void kernel_launch(void* const* d_in, const int* in_sizes, int n_in,
                              void* d_out, int out_size, void* d_ws, size_t ws_size,
                              hipStream_t stream) {
    const float* x0 = (const float*)d_in[0];
    const float* xk = (const float*)d_in[1];
    const float* W  = (const float*)d_in[2];
    const float* bi = (const float*)d_in[3];
    float* out = (float*)d_out;

    u16* W3 = (u16*)d_ws;                      // 655360 shorts = 1.31 MB

    w3_kernel<<<NC * 2, 256, 0, stream>>>(W, W3);
    cin_main<<<NB, 512, 0, stream>>>(x0, xk, bi, W3, out);
}